// Round 1
// baseline (229.551 us; speedup 1.0000x reference)
//
#include <hip/hip_runtime.h>
#include <stdint.h>

// Problem constants
#define BB 4
#define CC 256
#define HH 96
#define WW 96
#define HP 98      // halo-padded spatial dim (1 halo each side)
#define CP 264     // padded channel stride in bf16 elems (264*2B = 528B = 132 words; 132 % 32 = 4 -> conflict-free b128 frag reads)
#define XE 50      // staged x entries per row (48 tile + 2 halo)

typedef __bf16 bf16x8 __attribute__((ext_vector_type(8)));
typedef float f32x4 __attribute__((ext_vector_type(4)));

__device__ __forceinline__ uint16_t f2bf(float f) {
    uint32_t u = __float_as_uint(f);
    u += 0x7FFFu + ((u >> 16) & 1u);   // round-to-nearest-even
    return (uint16_t)(u >> 16);
}

// ---------------------------------------------------------------------------
// Pre-kernel 1: cen (NCHW fp32) -> cenT [b][hy 98][hx 98][264] bf16, halo=0.
// One block per (y, b). Phase 1: coalesced float4 reads -> LDS [c][x].
// Phase 2: LDS -> packed 16B writes, channel-contiguous (coalesced).
// ---------------------------------------------------------------------------
__global__ void transpose_cen(const float* __restrict__ cen, uint16_t* __restrict__ cenT) {
    const int y = blockIdx.x, b = blockIdx.y, tid = threadIdx.x;
    __shared__ uint16_t ldsX[CC * 100];   // stride 100 ushorts: 8B-aligned packed writes

    #pragma unroll
    for (int i = 0; i < 24; ++i) {
        int f = i * 256 + tid;            // 0..6143 float4 chunks of this (b,y) plane
        int c = f / 24, xq = f % 24;
        float4 v = *(const float4*)(cen + ((((size_t)b * CC + c) * HH + y) * WW + xq * 4));
        uint2 pk;
        pk.x = (uint32_t)f2bf(v.x) | ((uint32_t)f2bf(v.y) << 16);
        pk.y = (uint32_t)f2bf(v.z) | ((uint32_t)f2bf(v.w) << 16);
        *(uint2*)(&ldsX[c * 100 + xq * 4]) = pk;
    }
    __syncthreads();
    #pragma unroll
    for (int i = 0; i < 12; ++i) {
        int t = i * 256 + tid;            // 0..3071
        int x = t % 96, cq = t / 96;      // cq: 8-channel chunk 0..31
        uint32_t w0, w1, w2, w3;
        w0 = (uint32_t)ldsX[(cq * 8 + 0) * 100 + x] | ((uint32_t)ldsX[(cq * 8 + 1) * 100 + x] << 16);
        w1 = (uint32_t)ldsX[(cq * 8 + 2) * 100 + x] | ((uint32_t)ldsX[(cq * 8 + 3) * 100 + x] << 16);
        w2 = (uint32_t)ldsX[(cq * 8 + 4) * 100 + x] | ((uint32_t)ldsX[(cq * 8 + 5) * 100 + x] << 16);
        w3 = (uint32_t)ldsX[(cq * 8 + 6) * 100 + x] | ((uint32_t)ldsX[(cq * 8 + 7) * 100 + x] << 16);
        size_t o = (((size_t)b * HP + (y + 1)) * HP + (x + 1)) * CP + cq * 8;
        *(uint4*)(cenT + o) = make_uint4(w0, w1, w2, w3);
    }
}

// ---------------------------------------------------------------------------
// Pre-kernel 2: W3 [9][256 n][256 k] fp32 -> W3bf [9][8 ks][256 n][32 k] bf16.
// B-fragment for (g,ks,ntile) then = 1KiB contiguous global chunk per wave.
// ---------------------------------------------------------------------------
__global__ void cvt_w3(const float* __restrict__ W3, uint16_t* __restrict__ W3bf) {
    int e = (blockIdx.x * 256 + threadIdx.x) * 4;   // 0..589823
    int g = e >> 16, rem = e & 65535, n = rem >> 8, k = rem & 255;
    float4 v = *(const float4*)(W3 + e);
    uint2 pk;
    pk.x = (uint32_t)f2bf(v.x) | ((uint32_t)f2bf(v.y) << 16);
    pk.y = (uint32_t)f2bf(v.z) | ((uint32_t)f2bf(v.w) << 16);
    size_t o = (((size_t)(g * 8 + (k >> 5)) * 256 + n) * 32) + (k & 31);
    *(uint2*)(W3bf + o) = pk;
}

// ---------------------------------------------------------------------------
// Main kernel: block = (xhalf, y, b), 512 threads (8 waves).
// M = 48 positions (3 tiles), N = 256 channels (wave w owns tiles 2w, 2w+1),
// K = 256 (8 steps of mfma_f32_16x16x32_bf16).
// A (shifted cen) from full-K-resident LDS tile; B (W3^T) direct from global.
// Fused per-position L2 norm + signed accumulation over the 9 groups.
// ---------------------------------------------------------------------------
__global__ void ecm_main(const float* __restrict__ cen, const uint16_t* __restrict__ cenT,
                         const uint16_t* __restrict__ W3bf, float* __restrict__ out) {
    const int tid = threadIdx.x;
    const int wv = tid >> 6, lane = tid & 63, m15 = lane & 15, q = lane >> 4;
    const int x0 = blockIdx.x * 48, y = blockIdx.y, b = blockIdx.z;

    __shared__ __align__(16) uint16_t ldsA[3 * XE * CP];   // 79200 B
    __shared__ float ldsN[48];

    // Stage A: rows (y-1, y, y+1) in halo coords = cenT rows y..y+2, x entries x0..x0+49.
    for (int r = 0; r < 3; ++r) {
        const uint4* gs = (const uint4*)(cenT + (((size_t)b * HP + (y + r)) * HP + x0) * CP);
        uint4* ls = (uint4*)(ldsA + r * XE * CP);
        for (int c2 = tid; c2 < XE * CP / 8; c2 += 512) ls[c2] = gs[c2];
    }

    const int DY[9] = {-1, -1, -1, 0, 1, 1, 1, 0, 0};
    const int DX[9] = {-1, 0, 1, 1, 1, 0, -1, -1, 0};

    f32x4 fin[3][2] = {};
    const int nb0 = ((wv * 2) * 16 + m15) * 32 + q * 8;      // ush offset in a [256][32] ks-block
    const int nb1 = ((wv * 2 + 1) * 16 + m15) * 32 + q * 8;

    for (int g = 0; g < 9; ++g) {
        const int dyr = DY[g] + 1, dx = DX[g];
        const float sgn = (g < 8) ? -1.f : 1.f;
        __syncthreads();                       // prior-g ldsN reads done (also: A staging done, g=0)
        if (tid < 48) ldsN[tid] = 0.f;
        __syncthreads();

        int aoff[3];
        #pragma unroll
        for (int mt = 0; mt < 3; ++mt)
            aoff[mt] = (dyr * XE + (mt * 16 + m15 + dx + 1)) * CP + q * 8;

        const uint16_t* w3g = W3bf + (size_t)g * 8 * 8192;

        f32x4 acc[3][2] = {};
        #pragma unroll
        for (int ks = 0; ks < 8; ++ks) {
            bf16x8 a0 = *(const bf16x8*)(ldsA + aoff[0] + ks * 32);
            bf16x8 a1 = *(const bf16x8*)(ldsA + aoff[1] + ks * 32);
            bf16x8 a2 = *(const bf16x8*)(ldsA + aoff[2] + ks * 32);
            bf16x8 b0 = *(const bf16x8*)(w3g + ks * 8192 + nb0);
            bf16x8 b1 = *(const bf16x8*)(w3g + ks * 8192 + nb1);
            acc[0][0] = __builtin_amdgcn_mfma_f32_16x16x32_bf16(a0, b0, acc[0][0], 0, 0, 0);
            acc[1][0] = __builtin_amdgcn_mfma_f32_16x16x32_bf16(a1, b0, acc[1][0], 0, 0, 0);
            acc[2][0] = __builtin_amdgcn_mfma_f32_16x16x32_bf16(a2, b0, acc[2][0], 0, 0, 0);
            acc[0][1] = __builtin_amdgcn_mfma_f32_16x16x32_bf16(a0, b1, acc[0][1], 0, 0, 0);
            acc[1][1] = __builtin_amdgcn_mfma_f32_16x16x32_bf16(a1, b1, acc[1][1], 0, 0, 0);
            acc[2][1] = __builtin_amdgcn_mfma_f32_16x16x32_bf16(a2, b1, acc[2][1], 0, 0, 0);
        }

        // Per-position ||Y||^2: D layout row(pos) = q*4+r (+16*mt), col(chan) = m15 (+16*ntile).
        float p2[3][4];
        #pragma unroll
        for (int mt = 0; mt < 3; ++mt)
            #pragma unroll
            for (int r = 0; r < 4; ++r)
                p2[mt][r] = acc[mt][0][r] * acc[mt][0][r] + acc[mt][1][r] * acc[mt][1][r];
        #pragma unroll
        for (int off = 1; off <= 8; off <<= 1)
            #pragma unroll
            for (int mt = 0; mt < 3; ++mt)
                #pragma unroll
                for (int r = 0; r < 4; ++r)
                    p2[mt][r] += __shfl_xor(p2[mt][r], off, 64);
        if (m15 == 0) {
            #pragma unroll
            for (int mt = 0; mt < 3; ++mt)
                #pragma unroll
                for (int r = 0; r < 4; ++r)
                    atomicAdd(&ldsN[mt * 16 + q * 4 + r], p2[mt][r]);
        }
        __syncthreads();

        #pragma unroll
        for (int mt = 0; mt < 3; ++mt)
            #pragma unroll
            for (int r = 0; r < 4; ++r) {
                float s = sgn / fmaxf(sqrtf(ldsN[mt * 16 + q * 4 + r]), 1e-12f);
                fin[mt][0][r] += acc[mt][0][r] * s;
                fin[mt][1][r] += acc[mt][1][r] * s;
            }
    }

    // Epilogue: out = fin + cen (fp32), float4 along x (positions q*4..q*4+3).
    #pragma unroll
    for (int mt = 0; mt < 3; ++mt)
        #pragma unroll
        for (int j = 0; j < 2; ++j) {
            int ch = (wv * 2 + j) * 16 + m15;
            int x = x0 + mt * 16 + q * 4;
            size_t o = (((size_t)b * CC + ch) * HH + y) * WW + x;
            f32x4 c4 = *(const f32x4*)(cen + o);
            f32x4 v = fin[mt][j] + c4;
            *(f32x4*)(out + o) = v;
        }
}

extern "C" void kernel_launch(void* const* d_in, const int* in_sizes, int n_in,
                              void* d_out, int out_size, void* d_ws, size_t ws_size,
                              hipStream_t stream) {
    const float* cen = (const float*)d_in[0];
    // d_in[1] = W1, d_in[2] = W2: dead code (softmax over size-1 axis == 1.0)
    const float* W3 = (const float*)d_in[3];
    float* out = (float*)d_out;

    uint16_t* cenT = (uint16_t*)d_ws;                         // [4][98][98][264] bf16 = 20,283,648 B
    const size_t cenT_elems = (size_t)BB * HP * HP * CP;
    uint16_t* W3bf = cenT + cenT_elems;                       // [9][8][256][32] bf16 = 1,179,648 B

    hipMemsetAsync(d_ws, 0, cenT_elems * sizeof(uint16_t), stream);   // zero halos + pad
    transpose_cen<<<dim3(HH, BB), 256, 0, stream>>>(cen, cenT);
    cvt_w3<<<576, 256, 0, stream>>>(W3, W3bf);
    ecm_main<<<dim3(2, HH, BB), 512, 0, stream>>>(cen, cenT, W3bf, out);
}